// Round 5
// baseline (169.864 us; speedup 1.0000x reference)
//
#include <hip/hip_runtime.h>

// Problem constants (reference: N=4, T=128, F=512, EMBED=128, NLOC=360)
#define NT 512    // N*T
#define FD 512    // F (freq bins / q positions)
#define ED 128    // EMBED
#define LD 360    // NLOC
#define QCH 4     // q-chunks per nt (redundant-read blocks for r/w overlap)

typedef float f32x4 __attribute__((ext_vector_type(4)));  // nontemporal-store-compatible

// ---------------------------------------------------------------------------
// Algebraic fact: einsum("neqk,ntve->ntqe", attention, values) has no shared
// contraction index between its operands: softmax over k sums to 1, so
//   out[n,t,q,:] = Wo @ (Wv @ sum_v value[n,t,v,:]) + bo, independent of q,
//   query, key, Wq, Wk.  (Validated rounds 1-3; absmax 0.125 << 0.76.)
//
// Round-3 post-mortem: fused kernel = 112 us; work ~= 21 (read) + ~57 (write)
// serialized because every block reads before it writes. This round: grid
// (QCH=4, NT) = 2048 blocks of 512 threads -> only 1024 resident -> two block
// generations; gen-2 reads overlap gen-1 writes. Each block redundantly reads
// the full 256 KB value[nt] tile (the 4 same-nt blocks are dispatch-adjacent
// -> L2/LLC hits; value fits entirely in the 256 MB Infinity Cache), computes
// G itself (no cross-block dependency), and streams its 128-row quarter of
// the output with nontemporal stores.
// ---------------------------------------------------------------------------

__global__ __launch_bounds__(512) void fused_attn(
    const float* __restrict__ value,   // [NT][FD][ED]
    const float* __restrict__ Wv,      // [ED][ED]  (row e, col c)
    const float* __restrict__ Wo,      // [LD][ED]  (row l, col e)
    const float* __restrict__ bo,      // [LD]
    float* __restrict__ out)           // [NT][FD][LD]
{
    const int qc  = blockIdx.x;        // 0..3  (fastest-varying -> same-nt adjacency)
    const int nt  = blockIdx.y;        // 0..511
    const int tid = threadIdx.x;

    __shared__ float sRed[16][ED];   // 8 KB partial v-sums
    __shared__ float sS[ED];         // S[c] = sum_v value[nt][v][c]
    __shared__ float sP[ED];         // P[e] = <Wv[e,:], S>
    __shared__ float sG[LD];         // G[l] = <Wo[l,:], P> + bo[l]

    // ---- Phase 1: v-reduction (256 KB; HBM once per nt, then L2/LLC) ----
    const int c4 = (tid & 31) * 4;   // f32 column group within a 512-B row
    const int vg = tid >> 5;         // 0..15 row subgroup
    const float* base = value + (size_t)nt * FD * ED;

    float4 acc; acc.x = 0.f; acc.y = 0.f; acc.z = 0.f; acc.w = 0.f;
    #pragma unroll 8
    for (int i = 0; i < 32; ++i) {   // rows vg, vg+16, ..., vg+496
        const float4 r = *(const float4*)&base[(size_t)(vg + 16 * i) * ED + c4];
        acc.x += r.x; acc.y += r.y; acc.z += r.z; acc.w += r.w;
    }
    *(float4*)&sRed[vg][c4] = acc;
    __syncthreads();

    if (tid < ED) {
        float s = 0.f;
        #pragma unroll
        for (int g = 0; g < 16; ++g) s += sRed[g][tid];
        sS[tid] = s;
    }
    __syncthreads();

    // ---- Phase 2: P = Wv * S  (Wv 64 KB, L2-resident) ----
    if (tid < ED) {
        const float* wr = Wv + (size_t)tid * ED;
        float p = 0.f;
        #pragma unroll
        for (int c = 0; c < ED; c += 4) {
            const float4 w4 = *(const float4*)&wr[c];
            const float4 s4 = *(const float4*)&sS[c];
            p += w4.x * s4.x + w4.y * s4.y + w4.z * s4.z + w4.w * s4.w;
        }
        sP[tid] = p;
    }
    __syncthreads();

    // ---- Phase 3: G = Wo * P + bo ----
    if (tid < LD) {
        const float* wr = Wo + (size_t)tid * ED;
        float g = bo[tid];
        #pragma unroll
        for (int e = 0; e < ED; e += 4) {
            const float4 w4 = *(const float4*)&wr[e];
            const float4 p4 = *(const float4*)&sP[e];
            g += w4.x * p4.x + w4.y * p4.y + w4.z * p4.z + w4.w * p4.w;
        }
        sG[tid] = g;
    }
    __syncthreads();

    // ---- Phase 4: stream 128 rows x 1440 B (180 KB, nontemporal stores) ----
    const int wave = tid >> 6;       // 0..7
    const int lane = tid & 63;
    const f32x4* sG4 = (const f32x4*)sG;        // 90 vec4
    f32x4 rA = sG4[lane];
    f32x4 rB = (f32x4)(0.f);
    if (lane < 26) rB = sG4[64 + lane];

    float* obase = out + ((size_t)nt * FD + (size_t)qc * (FD / QCH)) * LD;
    #pragma unroll 4
    for (int r = wave; r < FD / QCH; r += 8) {  // 16 rows per wave
        f32x4* row = (f32x4*)(obase + (size_t)r * LD);
        __builtin_nontemporal_store(rA, &row[lane]);          // 1024 B contiguous
        if (lane < 26)
            __builtin_nontemporal_store(rB, &row[64 + lane]); // 416 B contiguous
    }
}

extern "C" void kernel_launch(void* const* d_in, const int* in_sizes, int n_in,
                              void* d_out, int out_size, void* d_ws, size_t ws_size,
                              hipStream_t stream) {
    (void)in_sizes; (void)n_in; (void)out_size; (void)d_ws; (void)ws_size;
    // setup_inputs order: value, key, query, Wv, Wk, Wq, Wo, bo
    const float* value = (const float*)d_in[0];
    const float* Wv    = (const float*)d_in[3];
    const float* Wo    = (const float*)d_in[6];
    const float* bo    = (const float*)d_in[7];
    float* out = (float*)d_out;

    fused_attn<<<dim3(QCH, NT), dim3(512), 0, stream>>>(value, Wv, Wo, bo, out);
}

// Round 6
// 119.954 us; speedup vs baseline: 1.4161x; 1.4161x over previous
//
#include <hip/hip_runtime.h>

// Problem constants (reference: N=4, T=128, F=512, EMBED=128, NLOC=360)
#define NT 512    // N*T
#define FD 512    // F (freq bins / q positions)
#define ED 128    // EMBED
#define LD 360    // NLOC

// ---------------------------------------------------------------------------
// Algebraic fact: einsum("neqk,ntve->ntqe", attention, values) has no shared
// contraction index between its operands: softmax over k sums to 1, so
//   out[n,t,q,:] = Wo @ (Wv @ sum_v value[n,t,v,:]) + bo, independent of q,
//   query, key, Wq, Wk.  (Validated rounds 1-5; absmax 0.125 << 0.76.)
//
// History: R3 fused single-pass = 112 us. R5 redundant-read overlap = 170 us
// (4 same-nt blocks land on 4 different XCD L2s -> +384 MB HBM reads).
// This round: overlap WITHOUT redundancy — each block owns TWO tiles
// (A = b, B = b+256); tile B's load loop is fused with tile A's store loop
// (stores source registers, loads sink registers; no barrier in between),
// so the B-read hides under the A-write stream. Traffic unchanged:
// 128 MB read + 377 MB write.
// ---------------------------------------------------------------------------

__device__ __forceinline__ void reduce_project(
    int tid, int vg, int c4, const float4& acc,
    float (*sRed)[ED], float* sS, float* sP, float* sG,
    const float* __restrict__ Wv, const float* __restrict__ Wo,
    const float* __restrict__ bo)
{
    *(float4*)&sRed[vg][c4] = acc;
    __syncthreads();

    if (tid < ED) {
        float s = 0.f;
        #pragma unroll
        for (int g = 0; g < 16; ++g) s += sRed[g][tid];
        sS[tid] = s;
    }
    __syncthreads();

    if (tid < ED) {
        const float* wr = Wv + (size_t)tid * ED;
        float p = 0.f;
        #pragma unroll
        for (int c = 0; c < ED; c += 4) {
            const float4 w4 = *(const float4*)&wr[c];
            const float4 s4 = *(const float4*)&sS[c];
            p += w4.x * s4.x + w4.y * s4.y + w4.z * s4.z + w4.w * s4.w;
        }
        sP[tid] = p;
    }
    __syncthreads();

    if (tid < LD) {
        const float* wr = Wo + (size_t)tid * ED;
        float g = bo[tid];
        #pragma unroll
        for (int e = 0; e < ED; e += 4) {
            const float4 w4 = *(const float4*)&wr[e];
            const float4 p4 = *(const float4*)&sP[e];
            g += w4.x * p4.x + w4.y * p4.y + w4.z * p4.z + w4.w * p4.w;
        }
        sG[tid] = g;
    }
    __syncthreads();
}

__global__ __launch_bounds__(512) void fused_attn_pipe(
    const float* __restrict__ value,   // [NT][FD][ED]
    const float* __restrict__ Wv,      // [ED][ED]
    const float* __restrict__ Wo,      // [LD][ED]
    const float* __restrict__ bo,      // [LD]
    float* __restrict__ out)           // [NT][FD][LD]
{
    const int b   = blockIdx.x;        // 0..255
    const int tid = threadIdx.x;
    const int ntA = b;
    const int ntB = b + 256;

    __shared__ float sRed[16][ED];   // 8 KB
    __shared__ float sS[ED];
    __shared__ float sP[ED];
    __shared__ float sG[LD];

    const int c4   = (tid & 31) * 4; // f32 column group within a 512-B row
    const int vg   = tid >> 5;       // 0..15 row subgroup (loads)
    const int wave = tid >> 6;       // 0..7 (stores)
    const int lane = tid & 63;

    const float* baseA = value + (size_t)ntA * FD * ED;
    const float* baseB = value + (size_t)ntB * FD * ED;

    // ---- Phase 1: read tile A (256 KB) ----
    float4 acc; acc.x = 0.f; acc.y = 0.f; acc.z = 0.f; acc.w = 0.f;
    #pragma unroll 8
    for (int i = 0; i < 32; ++i) {
        const float4 r = *(const float4*)&baseA[(size_t)(vg + 16 * i) * ED + c4];
        acc.x += r.x; acc.y += r.y; acc.z += r.z; acc.w += r.w;
    }
    reduce_project(tid, vg, c4, acc, sRed, sS, sP, sG, Wv, Wo, bo);

    // Row image of G_A in registers.
    const float4* sG4 = (const float4*)sG;   // 90 float4
    float4 rA = sG4[lane];
    float4 rB; rB.x = 0.f; rB.y = 0.f; rB.z = 0.f; rB.w = 0.f;
    if (lane < 26) rB = sG4[64 + lane];

    // ---- Phase 2: store tile A (720 KB) || read tile B (256 KB) ----
    // Stores read only registers; loads write only registers -> no barrier,
    // compiler interleaves both memory streams.
    float* obaseA = out + (size_t)ntA * FD * LD;
    acc.x = 0.f; acc.y = 0.f; acc.z = 0.f; acc.w = 0.f;
    #pragma unroll 4
    for (int i = 0; i < 32; ++i) {
        const float4 r = *(const float4*)&baseB[(size_t)(vg + 16 * i) * ED + c4];
        float4* row0 = (float4*)(obaseA + (size_t)(wave + 16 * i) * LD);
        float4* row1 = (float4*)(obaseA + (size_t)(wave + 8 + 16 * i) * LD);
        row0[lane] = rA;
        if (lane < 26) row0[64 + lane] = rB;
        row1[lane] = rA;
        if (lane < 26) row1[64 + lane] = rB;
        acc.x += r.x; acc.y += r.y; acc.z += r.z; acc.w += r.w;
    }
    reduce_project(tid, vg, c4, acc, sRed, sS, sP, sG, Wv, Wo, bo);

    rA = sG4[lane];
    if (lane < 26) rB = sG4[64 + lane];

    // ---- Phase 3: store tile B (720 KB) ----
    float* obaseB = out + (size_t)ntB * FD * LD;
    #pragma unroll 4
    for (int r = wave; r < FD; r += 8) {
        float4* row = (float4*)(obaseB + (size_t)r * LD);
        row[lane] = rA;
        if (lane < 26) row[64 + lane] = rB;
    }
}

extern "C" void kernel_launch(void* const* d_in, const int* in_sizes, int n_in,
                              void* d_out, int out_size, void* d_ws, size_t ws_size,
                              hipStream_t stream) {
    (void)in_sizes; (void)n_in; (void)out_size; (void)d_ws; (void)ws_size;
    // setup_inputs order: value, key, query, Wv, Wk, Wq, Wo, bo
    const float* value = (const float*)d_in[0];
    const float* Wv    = (const float*)d_in[3];
    const float* Wo    = (const float*)d_in[6];
    const float* bo    = (const float*)d_in[7];
    float* out = (float*)d_out;

    fused_attn_pipe<<<dim3(NT / 2), dim3(512), 0, stream>>>(value, Wv, Wo, bo, out);
}